// Round 18
// baseline (376.543 us; speedup 1.0000x reference)
//
#include <hip/hip_runtime.h>

typedef __attribute__((ext_vector_type(8))) short short8;
typedef __attribute__((ext_vector_type(4))) float f32x4;

#define MFMA16(a, b, c) __builtin_amdgcn_mfma_f32_16x16x32_bf16((a), (b), (c), 0, 0, 0)

// raw barrier: LDS visibility only (lgkmcnt), leaves global prefetches (vmcnt) in flight
#define BAR() do { asm volatile("s_waitcnt lgkmcnt(0)" ::: "memory"); \
                   __builtin_amdgcn_s_barrier(); \
                   asm volatile("" ::: "memory"); } while (0)

template<int CTRL>
__device__ __forceinline__ float dpp_ror(float x) {
  return __builtin_bit_cast(float,
      __builtin_amdgcn_update_dpp(0, __builtin_bit_cast(int, x), CTRL, 0xF, 0xF, false));
}

__device__ __forceinline__ unsigned cvtpk(float lo, float hi) {
  unsigned r;
  asm("v_cvt_pk_bf16_f32 %0, %1, %2" : "=v"(r) : "v"(lo), "v"(hi));
  return r;
}

__device__ __forceinline__ unsigned short f2b(float f) {
  union { float f; unsigned u; } v; v.f = f;
  return (unsigned short)((v.u + 0x7FFFu + ((v.u >> 16) & 1u)) >> 16);  // RNE
}

// ---------------- prep kernels ----------------
__global__ void prep_wqkv(const float* __restrict__ qkv_w, unsigned short* __restrict__ wq) {
  int idx = blockIdx.x * 256 + threadIdx.x;   // 768*256
  int wcol = idx >> 8, k = idx & 255;
  float v = qkv_w[k * 768 + wcol];
  if (wcol < 256) v *= 0.125f;
  wq[idx] = f2b(v);
}

__global__ void prep_wproj(const float* __restrict__ proj_w, unsigned short* __restrict__ wp) {
  int idx = blockIdx.x * 256 + threadIdx.x;   // 256*256
  int col = idx >> 8, k = idx & 255;
  wp[idx] = f2b(proj_w[k * 256 + col]);
}

// comb3[w][h][j=key][i=query] f32: loads as f32x4 straight into the S accumulator.
__global__ void prep_comb3(const float* __restrict__ mask, const float* __restrict__ bias_table,
                           const int* __restrict__ rel_index, float* __restrict__ comb3) {
  int idx = blockIdx.x * 256 + threadIdx.x;   // 64*4*64*64 = 1048576
  int i = idx & 63, j = (idx >> 6) & 63, h = (idx >> 12) & 3, w = idx >> 14;
  float v;
  if (j >= 49) v = -1e30f;
  else if (i >= 49) v = 0.f;
  else v = mask[(w * 49 + i) * 49 + j] + bias_table[rel_index[i * 49 + j] * 4 + h];
  comb3[idx] = v;
}

// ---------------- fused window-attention kernel ----------------
// LDS (ushort units), padded strides. 53,504 B -> 3 blocks/CU.
#define XS   0        // [48][264]  x bf16 rows 0-47; later O rows 0-47
#define XLD  264
#define XR   12672    // [256]      x row 48; later O row 48
#define QPS  12928    // [64][72]   Q, later aliased by P (per-wave row slices)
#define KS   17536    // [64][72]   K
#define VT   22144    // [64][72]   V transposed: [dim][token]
#define SLD  72
#define LDS_TOT 26752 // ushorts = 53,504 B

__global__ __launch_bounds__(256, 3) void win_attn(
    const float* __restrict__ x, const float* __restrict__ qkv_b,
    const float* __restrict__ proj_b, const unsigned short* __restrict__ wq,
    const unsigned short* __restrict__ wp, const float* __restrict__ comb3,
    float* __restrict__ out)
{
  __shared__ alignas(16) unsigned short lds[LDS_TOT];
  const int b = blockIdx.x, tid = threadIdx.x;
  const int wv = tid >> 6, l = tid & 63, g = l >> 4, c = l & 15;

  // ---- Phase A: batch-issue ALL x loads, then convert ----
  {
    const f32x4* xb = (const f32x4*)(x + (size_t)b * (49 * 256));
    f32x4 xv[12];
    #pragma unroll
    for (int it = 0; it < 6; ++it) {
      int idx = tid + it * 256, row = idx >> 5, c8 = idx & 31;   // rows 0..47
      const f32x4* p = xb + row * 64 + c8 * 2;
      xv[2 * it] = p[0]; xv[2 * it + 1] = p[1];
    }
    f32x4 xr0, xr1;
    if (tid < 32) { const f32x4* p = xb + 48 * 64 + tid * 2; xr0 = p[0]; xr1 = p[1]; }
    #pragma unroll
    for (int it = 0; it < 6; ++it) {
      int idx = tid + it * 256, row = idx >> 5, c8 = idx & 31;
      uint4 pk = make_uint4(cvtpk(xv[2 * it].x, xv[2 * it].y),
                            cvtpk(xv[2 * it].z, xv[2 * it].w),
                            cvtpk(xv[2 * it + 1].x, xv[2 * it + 1].y),
                            cvtpk(xv[2 * it + 1].z, xv[2 * it + 1].w));
      *(uint4*)&lds[XS + row * XLD + c8 * 8] = pk;
    }
    if (tid < 32) {
      uint4 pk = make_uint4(cvtpk(xr0.x, xr0.y), cvtpk(xr0.z, xr0.w),
                            cvtpk(xr1.x, xr1.y), cvtpk(xr1.z, xr1.w));
      *(uint4*)&lds[XR + tid * 8] = pk;
    }
  }
  BAR();

  f32x4 zero4 = {0.f, 0.f, 0.f, 0.f};
  f32x4 oacc[4][4];
  #pragma unroll
  for (int h = 0; h < 4; ++h)
    #pragma unroll
    for (int nd = 0; nd < 4; ++nd) oacc[h][nd] = zero4;

  #pragma unroll
  for (int h = 0; h < 4; ++h) {
    // ---- comb3 prefetch (phase-local), straight into S acc ----
    const float* cb3 = comb3 + (((size_t)(b & 63)) * 4 + h) * 4096;
    f32x4 sacc[4];
    #pragma unroll
    for (int ni = 0; ni < 4; ++ni)
      sacc[ni] = *(const f32x4*)(cb3 + (ni * 16 + c) * 64 + wv * 16 + g * 4);

    // ---- B1: QKV GEMM, merged-dst + 2-deep weight lookahead (phase-local) ----
    f32x4 acc[3][4];
    #pragma unroll
    for (int dst = 0; dst < 3; ++dst)
      #pragma unroll
      for (int mi = 0; mi < 4; ++mi) acc[dst][mi] = zero4;

    const unsigned short* wbase = wq + ((size_t)(h * 64 + wv * 16 + c)) * 256 + g * 8;
    short8 wA0 = *(const short8*)(wbase);
    short8 wA1 = *(const short8*)(wbase + 65536);
    short8 wA2 = *(const short8*)(wbase + 131072);
    short8 wB0 = *(const short8*)(wbase + 32);
    short8 wB1 = *(const short8*)(wbase + 65536 + 32);
    short8 wB2 = *(const short8*)(wbase + 131072 + 32);
    #pragma unroll
    for (int ks = 0; ks < 8; ++ks) {
      short8 t0, t1, t2;
      if (ks < 6) {
        t0 = *(const short8*)(wbase + (ks + 2) * 32);
        t1 = *(const short8*)(wbase + 65536 + (ks + 2) * 32);
        t2 = *(const short8*)(wbase + 131072 + (ks + 2) * 32);
      }
      short8 a0 = *(const short8*)&lds[XS + (0 * 16 + c) * XLD + ks * 32 + g * 8];
      short8 a1 = *(const short8*)&lds[XS + (1 * 16 + c) * XLD + ks * 32 + g * 8];
      short8 a2 = *(const short8*)&lds[XS + (2 * 16 + c) * XLD + ks * 32 + g * 8];
      short8 a3 = *(const short8*)&lds[XR + ks * 32 + g * 8];   // broadcast row 48
      acc[0][0] = MFMA16(a0, wA0, acc[0][0]);
      acc[1][0] = MFMA16(a0, wA1, acc[1][0]);
      acc[2][0] = MFMA16(a0, wA2, acc[2][0]);
      acc[0][1] = MFMA16(a1, wA0, acc[0][1]);
      acc[1][1] = MFMA16(a1, wA1, acc[1][1]);
      acc[2][1] = MFMA16(a1, wA2, acc[2][1]);
      acc[0][2] = MFMA16(a2, wA0, acc[0][2]);
      acc[1][2] = MFMA16(a2, wA1, acc[1][2]);
      acc[2][2] = MFMA16(a2, wA2, acc[2][2]);
      acc[0][3] = MFMA16(a3, wA0, acc[0][3]);
      acc[1][3] = MFMA16(a3, wA1, acc[1][3]);
      acc[2][3] = MFMA16(a3, wA2, acc[2][3]);
      wA0 = wB0; wA1 = wB1; wA2 = wB2;
      if (ks < 6) { wB0 = t0; wB1 = t1; wB2 = t2; }
    }
    const float bq = qkv_b[h * 64 + wv * 16 + c] * 0.125f;   // SCALE folded into Q path
    const float bk = qkv_b[256 + h * 64 + wv * 16 + c];
    const float bv = qkv_b[512 + h * 64 + wv * 16 + c];
    const int d = wv * 16 + c;
    #pragma unroll
    for (int mi = 0; mi < 4; ++mi) {
      const int row0 = mi * 16 + g * 4;
      unsigned q01 = cvtpk(acc[0][mi][0] + bq, acc[0][mi][1] + bq);
      unsigned q23 = cvtpk(acc[0][mi][2] + bq, acc[0][mi][3] + bq);
      lds[QPS + (row0 + 0) * SLD + d] = (unsigned short)q01;
      lds[QPS + (row0 + 1) * SLD + d] = (unsigned short)(q01 >> 16);
      lds[QPS + (row0 + 2) * SLD + d] = (unsigned short)q23;
      lds[QPS + (row0 + 3) * SLD + d] = (unsigned short)(q23 >> 16);
      unsigned k01 = cvtpk(acc[1][mi][0] + bk, acc[1][mi][1] + bk);
      unsigned k23 = cvtpk(acc[1][mi][2] + bk, acc[1][mi][3] + bk);
      lds[KS + (row0 + 0) * SLD + d] = (unsigned short)k01;
      lds[KS + (row0 + 1) * SLD + d] = (unsigned short)(k01 >> 16);
      lds[KS + (row0 + 2) * SLD + d] = (unsigned short)k23;
      lds[KS + (row0 + 3) * SLD + d] = (unsigned short)(k23 >> 16);
      unsigned v01 = cvtpk(acc[2][mi][0] + bv, acc[2][mi][1] + bv);
      unsigned v23 = cvtpk(acc[2][mi][2] + bv, acc[2][mi][3] + bv);
      *(uint2*)&lds[VT + d * SLD + row0] = make_uint2(v01, v23);   // V transposed, b64
    }
    BAR();

    // ---- B2: S = comb3 + Q K^T (accumulator pre-loaded) ----
    #pragma unroll
    for (int kk = 0; kk < 2; ++kk) {
      short8 af = *(const short8*)&lds[QPS + (wv * 16 + c) * SLD + kk * 32 + g * 8];
      short8 b0 = *(const short8*)&lds[KS + (0 * 16 + c) * SLD + kk * 32 + g * 8];
      short8 b1 = *(const short8*)&lds[KS + (1 * 16 + c) * SLD + kk * 32 + g * 8];
      short8 b2 = *(const short8*)&lds[KS + (2 * 16 + c) * SLD + kk * 32 + g * 8];
      short8 b3 = *(const short8*)&lds[KS + (3 * 16 + c) * SLD + kk * 32 + g * 8];
      sacc[0] = MFMA16(af, b0, sacc[0]);
      sacc[1] = MFMA16(af, b1, sacc[1]);
      sacc[2] = MFMA16(af, b2, sacc[2]);
      sacc[3] = MFMA16(af, b3, sacc[3]);
    }

    // ---- B3: row max (dpp) + p = exp(S-m) in [0,1]; write UNNORMALIZED P;
    //      keep per-lane partial sums sl[r]; normalization deferred past B4 ----
    float sl[4];
    #pragma unroll
    for (int r = 0; r < 4; ++r) {
      float m = fmaxf(fmaxf(sacc[0][r], sacc[1][r]), fmaxf(sacc[2][r], sacc[3][r]));
      m = fmaxf(m, dpp_ror<0x128>(m));
      m = fmaxf(m, dpp_ror<0x124>(m));
      m = fmaxf(m, dpp_ror<0x122>(m));
      m = fmaxf(m, dpp_ror<0x121>(m));
      float p0 = __expf(sacc[0][r] - m), p1 = __expf(sacc[1][r] - m);
      float p2 = __expf(sacc[2][r] - m), p3 = __expf(sacc[3][r] - m);
      sl[r] = (p0 + p1) + (p2 + p3);
      const int row = wv * 16 + g * 4 + r;
      unsigned p01 = cvtpk(p0, p1);
      unsigned p23 = cvtpk(p2, p3);
      lds[QPS + row * SLD +  0 + c] = (unsigned short)p01;
      lds[QPS + row * SLD + 16 + c] = (unsigned short)(p01 >> 16);
      lds[QPS + row * SLD + 32 + c] = (unsigned short)p23;
      lds[QPS + row * SLD + 48 + c] = (unsigned short)(p23 >> 16);
    }

    // ---- B4: O_unnorm = P V ----
    #pragma unroll
    for (int kk = 0; kk < 2; ++kk) {
      short8 af = *(const short8*)&lds[QPS + (wv * 16 + c) * SLD + kk * 32 + g * 8];
      short8 b0 = *(const short8*)&lds[VT + (0 * 16 + c) * SLD + kk * 32 + g * 8];
      short8 b1 = *(const short8*)&lds[VT + (1 * 16 + c) * SLD + kk * 32 + g * 8];
      short8 b2 = *(const short8*)&lds[VT + (2 * 16 + c) * SLD + kk * 32 + g * 8];
      short8 b3 = *(const short8*)&lds[VT + (3 * 16 + c) * SLD + kk * 32 + g * 8];
      oacc[h][0] = MFMA16(af, b0, oacc[h][0]);
      oacc[h][1] = MFMA16(af, b1, oacc[h][1]);
      oacc[h][2] = MFMA16(af, b2, oacc[h][2]);
      oacc[h][3] = MFMA16(af, b3, oacc[h][3]);
    }

    // ---- deferred normalization: dpp row-sum + rcp + oacc scale (overlaps next B1) ----
    #pragma unroll
    for (int r = 0; r < 4; ++r) {
      float s = sl[r];
      s += dpp_ror<0x128>(s);
      s += dpp_ror<0x124>(s);
      s += dpp_ror<0x122>(s);
      s += dpp_ror<0x121>(s);
      const float inv = 1.0f / s;
      oacc[h][0][r] *= inv;
      oacc[h][1][r] *= inv;
      oacc[h][2][r] *= inv;
      oacc[h][3][r] *= inv;
    }
    BAR();   // protect QPS/KS/VT before next head overwrites
  }

  // ---- Phase D weight prefetch (ks=0,1), issued before the phase-C LDS writes ----
  const unsigned short* wpb = wp + ((size_t)(wv * 64 + c)) * 256 + g * 8;
  short8 pA0 = *(const short8*)(wpb);
  short8 pA1 = *(const short8*)(wpb + 4096);
  short8 pA2 = *(const short8*)(wpb + 8192);
  short8 pA3 = *(const short8*)(wpb + 12288);
  short8 pB0 = *(const short8*)(wpb + 32);
  short8 pB1 = *(const short8*)(wpb + 4096 + 32);
  short8 pB2 = *(const short8*)(wpb + 8192 + 32);
  short8 pB3 = *(const short8*)(wpb + 12288 + 32);

  // ---- Phase C: O bf16 -> XS rows 0-47 (waves 0-2) + XR row 48 (wave 3, g==0) ----
  if (wv < 3) {
    #pragma unroll
    for (int h = 0; h < 4; ++h)
      #pragma unroll
      for (int nd = 0; nd < 4; ++nd) {
        const int colc = h * 64 + nd * 16 + c, row0 = wv * 16 + g * 4;
        unsigned o01 = cvtpk(oacc[h][nd][0], oacc[h][nd][1]);
        unsigned o23 = cvtpk(oacc[h][nd][2], oacc[h][nd][3]);
        lds[XS + (row0 + 0) * XLD + colc] = (unsigned short)o01;
        lds[XS + (row0 + 1) * XLD + colc] = (unsigned short)(o01 >> 16);
        lds[XS + (row0 + 2) * XLD + colc] = (unsigned short)o23;
        lds[XS + (row0 + 3) * XLD + colc] = (unsigned short)(o23 >> 16);
      }
  } else if (g == 0) {   // wave 3 holds rows 48-63; only row 48 is real
    #pragma unroll
    for (int h = 0; h < 4; ++h)
      #pragma unroll
      for (int nd = 0; nd < 4; ++nd)
        lds[XR + h * 64 + nd * 16 + c] =
            (unsigned short)cvtpk(oacc[h][nd][0], oacc[h][nd][0]);
  }
  BAR();

  // ---- Phase D: out = O @ proj_w + proj_b, k-outer, 2-deep weight lookahead ----
  f32x4 pacc[4][4];   // [nj][mi]
  #pragma unroll
  for (int nj = 0; nj < 4; ++nj)
    #pragma unroll
    for (int mi = 0; mi < 4; ++mi) pacc[nj][mi] = zero4;

  #pragma unroll
  for (int ks = 0; ks < 8; ++ks) {
    short8 t0, t1, t2, t3;
    if (ks < 6) {
      t0 = *(const short8*)(wpb + (ks + 2) * 32);
      t1 = *(const short8*)(wpb + 4096 + (ks + 2) * 32);
      t2 = *(const short8*)(wpb + 8192 + (ks + 2) * 32);
      t3 = *(const short8*)(wpb + 12288 + (ks + 2) * 32);
    }
    short8 a0 = *(const short8*)&lds[XS + (0 * 16 + c) * XLD + ks * 32 + g * 8];
    short8 a1 = *(const short8*)&lds[XS + (1 * 16 + c) * XLD + ks * 32 + g * 8];
    short8 a2 = *(const short8*)&lds[XS + (2 * 16 + c) * XLD + ks * 32 + g * 8];
    short8 a3 = *(const short8*)&lds[XR + ks * 32 + g * 8];   // broadcast O row 48
    pacc[0][0] = MFMA16(a0, pA0, pacc[0][0]);
    pacc[1][0] = MFMA16(a0, pA1, pacc[1][0]);
    pacc[2][0] = MFMA16(a0, pA2, pacc[2][0]);
    pacc[3][0] = MFMA16(a0, pA3, pacc[3][0]);
    pacc[0][1] = MFMA16(a1, pA0, pacc[0][1]);
    pacc[1][1] = MFMA16(a1, pA1, pacc[1][1]);
    pacc[2][1] = MFMA16(a1, pA2, pacc[2][1]);
    pacc[3][1] = MFMA16(a1, pA3, pacc[3][1]);
    pacc[0][2] = MFMA16(a2, pA0, pacc[0][2]);
    pacc[1][2] = MFMA16(a2, pA1, pacc[1][2]);
    pacc[2][2] = MFMA16(a2, pA2, pacc[2][2]);
    pacc[3][2] = MFMA16(a2, pA3, pacc[3][2]);
    pacc[0][3] = MFMA16(a3, pA0, pacc[0][3]);
    pacc[1][3] = MFMA16(a3, pA1, pacc[1][3]);
    pacc[2][3] = MFMA16(a3, pA2, pacc[2][3]);
    pacc[3][3] = MFMA16(a3, pA3, pacc[3][3]);
    pA0 = pB0; pA1 = pB1; pA2 = pB2; pA3 = pB3;
    if (ks < 6) { pB0 = t0; pB1 = t1; pB2 = t2; pB3 = t3; }
  }
  #pragma unroll
  for (int nj = 0; nj < 4; ++nj) {
    const float pb = proj_b[wv * 64 + nj * 16 + c];
    #pragma unroll
    for (int mi = 0; mi < 3; ++mi) {
      #pragma unroll
      for (int r = 0; r < 4; ++r) {
        const int row = mi * 16 + g * 4 + r;   // 0..47, always valid
        out[((size_t)b * 49 + row) * 256 + wv * 64 + nj * 16 + c] = pacc[nj][mi][r] + pb;
      }
    }
    if (g == 0)   // mi=3 tile: only row 48 is real
      out[((size_t)b * 49 + 48) * 256 + wv * 64 + nj * 16 + c] = pacc[nj][3][0] + pb;
  }
}

extern "C" void kernel_launch(void* const* d_in, const int* in_sizes, int n_in,
                              void* d_out, int out_size, void* d_ws, size_t ws_size,
                              hipStream_t stream) {
  const float* x          = (const float*)d_in[0];
  const float* mask       = (const float*)d_in[1];
  const float* qkv_w      = (const float*)d_in[2];
  const float* qkv_b      = (const float*)d_in[3];
  const float* proj_w     = (const float*)d_in[4];
  const float* proj_b     = (const float*)d_in[5];
  const float* bias_table = (const float*)d_in[6];
  const int*   rel_index  = (const int*)d_in[7];
  float* out = (float*)d_out;

  unsigned short* wq = (unsigned short*)d_ws;            // 768*256 bf16
  unsigned short* wp = wq + 768 * 256;                   // 256*256 bf16
  float* comb3 = (float*)(wp + 256 * 256);               // 64*4*64*64 f32 (~4 MB)

  prep_wqkv<<<768, 256, 0, stream>>>(qkv_w, wq);
  prep_wproj<<<256, 256, 0, stream>>>(proj_w, wp);
  prep_comb3<<<4096, 256, 0, stream>>>(mask, bias_table, rel_index, comb3);
  win_attn<<<4096, 256, 0, stream>>>(x, qkv_b, proj_b, wq, wp, comb3, out);
}

// Round 19
// 330.426 us; speedup vs baseline: 1.1396x; 1.1396x over previous
//
#include <hip/hip_runtime.h>

typedef __attribute__((ext_vector_type(8))) short short8;
typedef __attribute__((ext_vector_type(4))) float f32x4;

#define MFMA16(a, b, c) __builtin_amdgcn_mfma_f32_16x16x32_bf16((a), (b), (c), 0, 0, 0)

// raw barrier: LDS visibility only (lgkmcnt), leaves global prefetches (vmcnt) in flight
#define BAR() do { asm volatile("s_waitcnt lgkmcnt(0)" ::: "memory"); \
                   __builtin_amdgcn_s_barrier(); \
                   asm volatile("" ::: "memory"); } while (0)

template<int CTRL>
__device__ __forceinline__ float dpp_ror(float x) {
  return __builtin_bit_cast(float,
      __builtin_amdgcn_update_dpp(0, __builtin_bit_cast(int, x), CTRL, 0xF, 0xF, false));
}

__device__ __forceinline__ unsigned cvtpk(float lo, float hi) {
  unsigned r;
  asm("v_cvt_pk_bf16_f32 %0, %1, %2" : "=v"(r) : "v"(lo), "v"(hi));
  return r;
}

__device__ __forceinline__ unsigned short f2b(float f) {
  union { float f; unsigned u; } v; v.f = f;
  return (unsigned short)((v.u + 0x7FFFu + ((v.u >> 16) & 1u)) >> 16);  // RNE
}

// ---------------- prep kernels ----------------
__global__ void prep_wqkv(const float* __restrict__ qkv_w, unsigned short* __restrict__ wq) {
  int idx = blockIdx.x * 256 + threadIdx.x;   // 768*256
  int wcol = idx >> 8, k = idx & 255;
  float v = qkv_w[k * 768 + wcol];
  if (wcol < 256) v *= 0.125f;
  wq[idx] = f2b(v);
}

__global__ void prep_wproj(const float* __restrict__ proj_w, unsigned short* __restrict__ wp) {
  int idx = blockIdx.x * 256 + threadIdx.x;   // 256*256
  int col = idx >> 8, k = idx & 255;
  wp[idx] = f2b(proj_w[k * 256 + col]);
}

// comb3[w][h][j=key][i=query] f32: loads as f32x4 straight into the S accumulator.
__global__ void prep_comb3(const float* __restrict__ mask, const float* __restrict__ bias_table,
                           const int* __restrict__ rel_index, float* __restrict__ comb3) {
  int idx = blockIdx.x * 256 + threadIdx.x;   // 64*4*64*64 = 1048576
  int i = idx & 63, j = (idx >> 6) & 63, h = (idx >> 12) & 3, w = idx >> 14;
  float v;
  if (j >= 49) v = -1e30f;
  else if (i >= 49) v = 0.f;
  else v = mask[(w * 49 + i) * 49 + j] + bias_table[rel_index[i * 49 + j] * 4 + h];
  comb3[idx] = v;
}

// ---------------- fused window-attention kernel ----------------
// LDS (ushort units), padded strides. 53,504 B -> 3 blocks/CU.
#define XS   0        // [48][264]  x bf16 rows 0-47; later O rows 0-47
#define XLD  264
#define XR   12672    // [256]      x row 48; later O row 48
#define QPS  12928    // [64][72]   Q, later aliased by P (per-wave row slices)
#define KS   17536    // [64][72]   K
#define VT   22144    // [64][72]   V transposed: [dim][token]
#define SLD  72
#define LDS_TOT 26752 // ushorts = 53,504 B

__global__ __launch_bounds__(256, 3) void win_attn(
    const float* __restrict__ x, const float* __restrict__ qkv_b,
    const float* __restrict__ proj_b, const unsigned short* __restrict__ wq,
    const unsigned short* __restrict__ wp, const float* __restrict__ comb3,
    float* __restrict__ out)
{
  __shared__ alignas(16) unsigned short lds[LDS_TOT];
  const int b = blockIdx.x, tid = threadIdx.x;
  const int wv = tid >> 6, l = tid & 63, g = l >> 4, c = l & 15;

  // ---- Phase A: batch-issue ALL x loads, then convert ----
  {
    const f32x4* xb = (const f32x4*)(x + (size_t)b * (49 * 256));
    f32x4 xv[12];
    #pragma unroll
    for (int it = 0; it < 6; ++it) {
      int idx = tid + it * 256, row = idx >> 5, c8 = idx & 31;   // rows 0..47
      const f32x4* p = xb + row * 64 + c8 * 2;
      xv[2 * it] = p[0]; xv[2 * it + 1] = p[1];
    }
    f32x4 xr0, xr1;
    if (tid < 32) { const f32x4* p = xb + 48 * 64 + tid * 2; xr0 = p[0]; xr1 = p[1]; }
    #pragma unroll
    for (int it = 0; it < 6; ++it) {
      int idx = tid + it * 256, row = idx >> 5, c8 = idx & 31;
      uint4 pk = make_uint4(cvtpk(xv[2 * it].x, xv[2 * it].y),
                            cvtpk(xv[2 * it].z, xv[2 * it].w),
                            cvtpk(xv[2 * it + 1].x, xv[2 * it + 1].y),
                            cvtpk(xv[2 * it + 1].z, xv[2 * it + 1].w));
      *(uint4*)&lds[XS + row * XLD + c8 * 8] = pk;
    }
    if (tid < 32) {
      uint4 pk = make_uint4(cvtpk(xr0.x, xr0.y), cvtpk(xr0.z, xr0.w),
                            cvtpk(xr1.x, xr1.y), cvtpk(xr1.z, xr1.w));
      *(uint4*)&lds[XR + tid * 8] = pk;
    }
  }
  BAR();

  f32x4 zero4 = {0.f, 0.f, 0.f, 0.f};
  f32x4 oacc[4][4];
  #pragma unroll
  for (int h = 0; h < 4; ++h)
    #pragma unroll
    for (int nd = 0; nd < 4; ++nd) oacc[h][nd] = zero4;

  #pragma unroll
  for (int h = 0; h < 4; ++h) {
    // ---- comb3 prefetch (phase-local), straight into S acc ----
    const float* cb3 = comb3 + (((size_t)(b & 63)) * 4 + h) * 4096;
    f32x4 sacc[4];
    #pragma unroll
    for (int ni = 0; ni < 4; ++ni)
      sacc[ni] = *(const f32x4*)(cb3 + (ni * 16 + c) * 64 + wv * 16 + g * 4);

    // ---- B1: QKV GEMM, merged-dst + 2-deep weight lookahead (phase-local) ----
    f32x4 acc[3][4];
    #pragma unroll
    for (int dst = 0; dst < 3; ++dst)
      #pragma unroll
      for (int mi = 0; mi < 4; ++mi) acc[dst][mi] = zero4;

    const unsigned short* wbase = wq + ((size_t)(h * 64 + wv * 16 + c)) * 256 + g * 8;
    short8 wA0 = *(const short8*)(wbase);
    short8 wA1 = *(const short8*)(wbase + 65536);
    short8 wA2 = *(const short8*)(wbase + 131072);
    short8 wB0 = *(const short8*)(wbase + 32);
    short8 wB1 = *(const short8*)(wbase + 65536 + 32);
    short8 wB2 = *(const short8*)(wbase + 131072 + 32);
    #pragma unroll
    for (int ks = 0; ks < 8; ++ks) {
      short8 t0, t1, t2;
      if (ks < 6) {
        t0 = *(const short8*)(wbase + (ks + 2) * 32);
        t1 = *(const short8*)(wbase + 65536 + (ks + 2) * 32);
        t2 = *(const short8*)(wbase + 131072 + (ks + 2) * 32);
      }
      short8 a0 = *(const short8*)&lds[XS + (0 * 16 + c) * XLD + ks * 32 + g * 8];
      short8 a1 = *(const short8*)&lds[XS + (1 * 16 + c) * XLD + ks * 32 + g * 8];
      short8 a2 = *(const short8*)&lds[XS + (2 * 16 + c) * XLD + ks * 32 + g * 8];
      short8 a3 = *(const short8*)&lds[XR + ks * 32 + g * 8];   // broadcast row 48
      acc[0][0] = MFMA16(a0, wA0, acc[0][0]);
      acc[1][0] = MFMA16(a0, wA1, acc[1][0]);
      acc[2][0] = MFMA16(a0, wA2, acc[2][0]);
      acc[0][1] = MFMA16(a1, wA0, acc[0][1]);
      acc[1][1] = MFMA16(a1, wA1, acc[1][1]);
      acc[2][1] = MFMA16(a1, wA2, acc[2][1]);
      acc[0][2] = MFMA16(a2, wA0, acc[0][2]);
      acc[1][2] = MFMA16(a2, wA1, acc[1][2]);
      acc[2][2] = MFMA16(a2, wA2, acc[2][2]);
      acc[0][3] = MFMA16(a3, wA0, acc[0][3]);
      acc[1][3] = MFMA16(a3, wA1, acc[1][3]);
      acc[2][3] = MFMA16(a3, wA2, acc[2][3]);
      wA0 = wB0; wA1 = wB1; wA2 = wB2;
      if (ks < 6) { wB0 = t0; wB1 = t1; wB2 = t2; }
    }
    const float bq = qkv_b[h * 64 + wv * 16 + c] * 0.125f;   // SCALE folded into Q path
    const float bk = qkv_b[256 + h * 64 + wv * 16 + c];
    const float bv = qkv_b[512 + h * 64 + wv * 16 + c];
    const int d = wv * 16 + c;
    #pragma unroll
    for (int mi = 0; mi < 4; ++mi) {
      const int row0 = mi * 16 + g * 4;
      unsigned q01 = cvtpk(acc[0][mi][0] + bq, acc[0][mi][1] + bq);
      unsigned q23 = cvtpk(acc[0][mi][2] + bq, acc[0][mi][3] + bq);
      lds[QPS + (row0 + 0) * SLD + d] = (unsigned short)q01;
      lds[QPS + (row0 + 1) * SLD + d] = (unsigned short)(q01 >> 16);
      lds[QPS + (row0 + 2) * SLD + d] = (unsigned short)q23;
      lds[QPS + (row0 + 3) * SLD + d] = (unsigned short)(q23 >> 16);
      unsigned k01 = cvtpk(acc[1][mi][0] + bk, acc[1][mi][1] + bk);
      unsigned k23 = cvtpk(acc[1][mi][2] + bk, acc[1][mi][3] + bk);
      lds[KS + (row0 + 0) * SLD + d] = (unsigned short)k01;
      lds[KS + (row0 + 1) * SLD + d] = (unsigned short)(k01 >> 16);
      lds[KS + (row0 + 2) * SLD + d] = (unsigned short)k23;
      lds[KS + (row0 + 3) * SLD + d] = (unsigned short)(k23 >> 16);
      unsigned v01 = cvtpk(acc[2][mi][0] + bv, acc[2][mi][1] + bv);
      unsigned v23 = cvtpk(acc[2][mi][2] + bv, acc[2][mi][3] + bv);
      *(uint2*)&lds[VT + d * SLD + row0] = make_uint2(v01, v23);   // V transposed, b64
    }
    BAR();

    // ---- B2: S = comb3 + Q K^T (accumulator pre-loaded) ----
    #pragma unroll
    for (int kk = 0; kk < 2; ++kk) {
      short8 af = *(const short8*)&lds[QPS + (wv * 16 + c) * SLD + kk * 32 + g * 8];
      short8 b0 = *(const short8*)&lds[KS + (0 * 16 + c) * SLD + kk * 32 + g * 8];
      short8 b1 = *(const short8*)&lds[KS + (1 * 16 + c) * SLD + kk * 32 + g * 8];
      short8 b2 = *(const short8*)&lds[KS + (2 * 16 + c) * SLD + kk * 32 + g * 8];
      short8 b3 = *(const short8*)&lds[KS + (3 * 16 + c) * SLD + kk * 32 + g * 8];
      sacc[0] = MFMA16(af, b0, sacc[0]);
      sacc[1] = MFMA16(af, b1, sacc[1]);
      sacc[2] = MFMA16(af, b2, sacc[2]);
      sacc[3] = MFMA16(af, b3, sacc[3]);
    }

    // ---- B3: row softmax (16-lane DPP rotate-reduce), P -> QPS (own rows) ----
    #pragma unroll
    for (int r = 0; r < 4; ++r) {
      float m = fmaxf(fmaxf(sacc[0][r], sacc[1][r]), fmaxf(sacc[2][r], sacc[3][r]));
      m = fmaxf(m, dpp_ror<0x128>(m));
      m = fmaxf(m, dpp_ror<0x124>(m));
      m = fmaxf(m, dpp_ror<0x122>(m));
      m = fmaxf(m, dpp_ror<0x121>(m));
      float p[4], s;
      p[0] = __expf(sacc[0][r] - m); p[1] = __expf(sacc[1][r] - m);
      p[2] = __expf(sacc[2][r] - m); p[3] = __expf(sacc[3][r] - m);
      s = (p[0] + p[1]) + (p[2] + p[3]);
      s += dpp_ror<0x128>(s);
      s += dpp_ror<0x124>(s);
      s += dpp_ror<0x122>(s);
      s += dpp_ror<0x121>(s);
      const float inv = 1.0f / s;
      const int row = wv * 16 + g * 4 + r;
      unsigned p01 = cvtpk(p[0] * inv, p[1] * inv);
      unsigned p23 = cvtpk(p[2] * inv, p[3] * inv);
      lds[QPS + row * SLD +  0 + c] = (unsigned short)p01;
      lds[QPS + row * SLD + 16 + c] = (unsigned short)(p01 >> 16);
      lds[QPS + row * SLD + 32 + c] = (unsigned short)p23;
      lds[QPS + row * SLD + 48 + c] = (unsigned short)(p23 >> 16);
    }

    // ---- B4: O_h = P V (accumulate per-head in regs) ----
    #pragma unroll
    for (int kk = 0; kk < 2; ++kk) {
      short8 af = *(const short8*)&lds[QPS + (wv * 16 + c) * SLD + kk * 32 + g * 8];
      short8 b0 = *(const short8*)&lds[VT + (0 * 16 + c) * SLD + kk * 32 + g * 8];
      short8 b1 = *(const short8*)&lds[VT + (1 * 16 + c) * SLD + kk * 32 + g * 8];
      short8 b2 = *(const short8*)&lds[VT + (2 * 16 + c) * SLD + kk * 32 + g * 8];
      short8 b3 = *(const short8*)&lds[VT + (3 * 16 + c) * SLD + kk * 32 + g * 8];
      oacc[h][0] = MFMA16(af, b0, oacc[h][0]);
      oacc[h][1] = MFMA16(af, b1, oacc[h][1]);
      oacc[h][2] = MFMA16(af, b2, oacc[h][2]);
      oacc[h][3] = MFMA16(af, b3, oacc[h][3]);
    }
    BAR();   // protect QPS/KS/VT before next head overwrites
  }

  // ---- Phase D weight prefetch (ks=0,1), issued before the phase-C LDS writes ----
  const unsigned short* wpb = wp + ((size_t)(wv * 64 + c)) * 256 + g * 8;
  short8 pA0 = *(const short8*)(wpb);
  short8 pA1 = *(const short8*)(wpb + 4096);
  short8 pA2 = *(const short8*)(wpb + 8192);
  short8 pA3 = *(const short8*)(wpb + 12288);
  short8 pB0 = *(const short8*)(wpb + 32);
  short8 pB1 = *(const short8*)(wpb + 4096 + 32);
  short8 pB2 = *(const short8*)(wpb + 8192 + 32);
  short8 pB3 = *(const short8*)(wpb + 12288 + 32);

  // ---- Phase C: O bf16 -> XS rows 0-47 (waves 0-2) + XR row 48 (wave 3, g==0) ----
  if (wv < 3) {
    #pragma unroll
    for (int h = 0; h < 4; ++h)
      #pragma unroll
      for (int nd = 0; nd < 4; ++nd) {
        const int colc = h * 64 + nd * 16 + c, row0 = wv * 16 + g * 4;
        unsigned o01 = cvtpk(oacc[h][nd][0], oacc[h][nd][1]);
        unsigned o23 = cvtpk(oacc[h][nd][2], oacc[h][nd][3]);
        lds[XS + (row0 + 0) * XLD + colc] = (unsigned short)o01;
        lds[XS + (row0 + 1) * XLD + colc] = (unsigned short)(o01 >> 16);
        lds[XS + (row0 + 2) * XLD + colc] = (unsigned short)o23;
        lds[XS + (row0 + 3) * XLD + colc] = (unsigned short)(o23 >> 16);
      }
  } else if (g == 0) {   // wave 3 holds rows 48-63; only row 48 is real
    #pragma unroll
    for (int h = 0; h < 4; ++h)
      #pragma unroll
      for (int nd = 0; nd < 4; ++nd)
        lds[XR + h * 64 + nd * 16 + c] =
            (unsigned short)cvtpk(oacc[h][nd][0], oacc[h][nd][0]);
  }
  BAR();

  // ---- Phase D: out = O @ proj_w + proj_b, k-outer, 2-deep weight lookahead ----
  f32x4 pacc[4][4];   // [nj][mi]
  #pragma unroll
  for (int nj = 0; nj < 4; ++nj)
    #pragma unroll
    for (int mi = 0; mi < 4; ++mi) pacc[nj][mi] = zero4;

  #pragma unroll
  for (int ks = 0; ks < 8; ++ks) {
    short8 t0, t1, t2, t3;
    if (ks < 6) {
      t0 = *(const short8*)(wpb + (ks + 2) * 32);
      t1 = *(const short8*)(wpb + 4096 + (ks + 2) * 32);
      t2 = *(const short8*)(wpb + 8192 + (ks + 2) * 32);
      t3 = *(const short8*)(wpb + 12288 + (ks + 2) * 32);
    }
    short8 a0 = *(const short8*)&lds[XS + (0 * 16 + c) * XLD + ks * 32 + g * 8];
    short8 a1 = *(const short8*)&lds[XS + (1 * 16 + c) * XLD + ks * 32 + g * 8];
    short8 a2 = *(const short8*)&lds[XS + (2 * 16 + c) * XLD + ks * 32 + g * 8];
    short8 a3 = *(const short8*)&lds[XR + ks * 32 + g * 8];   // broadcast O row 48
    pacc[0][0] = MFMA16(a0, pA0, pacc[0][0]);
    pacc[1][0] = MFMA16(a0, pA1, pacc[1][0]);
    pacc[2][0] = MFMA16(a0, pA2, pacc[2][0]);
    pacc[3][0] = MFMA16(a0, pA3, pacc[3][0]);
    pacc[0][1] = MFMA16(a1, pA0, pacc[0][1]);
    pacc[1][1] = MFMA16(a1, pA1, pacc[1][1]);
    pacc[2][1] = MFMA16(a1, pA2, pacc[2][1]);
    pacc[3][1] = MFMA16(a1, pA3, pacc[3][1]);
    pacc[0][2] = MFMA16(a2, pA0, pacc[0][2]);
    pacc[1][2] = MFMA16(a2, pA1, pacc[1][2]);
    pacc[2][2] = MFMA16(a2, pA2, pacc[2][2]);
    pacc[3][2] = MFMA16(a2, pA3, pacc[3][2]);
    pacc[0][3] = MFMA16(a3, pA0, pacc[0][3]);
    pacc[1][3] = MFMA16(a3, pA1, pacc[1][3]);
    pacc[2][3] = MFMA16(a3, pA2, pacc[2][3]);
    pacc[3][3] = MFMA16(a3, pA3, pacc[3][3]);
    pA0 = pB0; pA1 = pB1; pA2 = pB2; pA3 = pB3;
    if (ks < 6) { pB0 = t0; pB1 = t1; pB2 = t2; pB3 = t3; }
  }
  #pragma unroll
  for (int nj = 0; nj < 4; ++nj) {
    const float pb = proj_b[wv * 64 + nj * 16 + c];
    #pragma unroll
    for (int mi = 0; mi < 3; ++mi) {
      #pragma unroll
      for (int r = 0; r < 4; ++r) {
        const int row = mi * 16 + g * 4 + r;   // 0..47, always valid
        out[((size_t)b * 49 + row) * 256 + wv * 64 + nj * 16 + c] = pacc[nj][mi][r] + pb;
      }
    }
    if (g == 0)   // mi=3 tile: only row 48 is real
      out[((size_t)b * 49 + 48) * 256 + wv * 64 + nj * 16 + c] = pacc[nj][3][0] + pb;
  }
}

extern "C" void kernel_launch(void* const* d_in, const int* in_sizes, int n_in,
                              void* d_out, int out_size, void* d_ws, size_t ws_size,
                              hipStream_t stream) {
  const float* x          = (const float*)d_in[0];
  const float* mask       = (const float*)d_in[1];
  const float* qkv_w      = (const float*)d_in[2];
  const float* qkv_b      = (const float*)d_in[3];
  const float* proj_w     = (const float*)d_in[4];
  const float* proj_b     = (const float*)d_in[5];
  const float* bias_table = (const float*)d_in[6];
  const int*   rel_index  = (const int*)d_in[7];
  float* out = (float*)d_out;

  unsigned short* wq = (unsigned short*)d_ws;            // 768*256 bf16
  unsigned short* wp = wq + 768 * 256;                   // 256*256 bf16
  float* comb3 = (float*)(wp + 256 * 256);               // 64*4*64*64 f32 (~4 MB)

  prep_wqkv<<<768, 256, 0, stream>>>(qkv_w, wq);
  prep_wproj<<<256, 256, 0, stream>>>(proj_w, wp);
  prep_comb3<<<4096, 256, 0, stream>>>(mask, bias_table, rel_index, comb3);
  win_attn<<<4096, 256, 0, stream>>>(x, qkv_b, proj_b, wq, wp, comb3, out);
}